// Round 2
// 1293.708 us; speedup vs baseline: 1.0614x; 1.0614x over previous
//
#include <hip/hip_runtime.h>
#include <math.h>

#define MU_F 0.1f
#define SHRINK_F 0.01f   // LMBD * MU
#define BN_EPS_F 1e-5f

typedef _Float16 half_t;
typedef _Float16 half8 __attribute__((ext_vector_type(8)));
typedef float f32x4 __attribute__((ext_vector_type(4)));

// async global->LDS, 16B per lane. LDS dest is wave-uniform base + lane*16.
__device__ __forceinline__ void gll16(const half_t* g, half_t* l) {
    __builtin_amdgcn_global_load_lds(
        (const __attribute__((address_space(1))) void*)g,
        (__attribute__((address_space(3))) void*)l, 16, 0, 0);
}

// counted-vmcnt wait + raw barrier, split per the verified 8-phase idiom
// (separate asm statements + sched_barrier(0) fence; rule #18 hygiene).
#define VM_WAIT_BARRIER(N) do {                                   \
    asm volatile("s_waitcnt vmcnt(" #N ")" ::: "memory");         \
    __builtin_amdgcn_s_barrier();                                 \
    __builtin_amdgcn_sched_barrier(0);                            \
} while (0)

// ---------------------------------------------------------------------------
// MFMA implicit-GEMM conv, m97-style async pipeline:
//   block = 128co x 64px (batch folded into px: NPX = 32*Hd*Wd, exact 64-tiles)
//   2 waves of 64co x 64px (waves split co, share B) -> 16 MFMA : 8 ds_read_b128
//   staging via global_load_lds dwordx4 into 3 LDS buffers (12KB each),
//   counted s_waitcnt vmcnt(6) + raw s_barrier: chunk k+2 issued at iter k,
//   stays in flight across two barriers (never drained to 0 in the loop).
//   OOB taps -> 256B zero page (DMA is unconditional per row).
//   LDS: 192 rows x 64B linear (A rows 0..127, B rows 128..191); 16B slot
//   XOR-swizzle (slot = q ^ (row&3)) applied on global SOURCE and on ds_read
//   -> both sides share the same involution (rule 21), b128 reads conflict-lite.
//   XCD-chunked blockIdx.x swizzle (gridDim.x % 8 == 0 at all call sites).
// MODE 0: fwd conv stride S pad PAD; MODE 1: convT s1 (pad 1);
// MODE 2: convT s2 (pad 1, outpad 1) via parity-quadrant px mapping.
// Frag layout (16x16x32): A row=l&15, k=(l>>4)*8+j ; B col=l&15 same k;
// C/D col=l&15, row=(l>>4)*4+reg  [m89-verified].
// ---------------------------------------------------------------------------
template<int KS, int S, int PAD, int MODE>
__global__ __launch_bounds__(128, 2)
void conv_big(const half_t* __restrict__ Ag, const half_t* __restrict__ Xh,
              float* __restrict__ outF, half_t* __restrict__ outH,
              const half_t* __restrict__ auxH, const float* __restrict__ auxF,
              int CA, int Cout, int Hin, int Win, int Hout, int Wout, int ptiles,
              float alpha, float beta, float delta, int relu1,
              const float* __restrict__ pscale, const float* __restrict__ pbias,
              const float* __restrict__ aux3, int relu2,
              const half_t* __restrict__ zpg)
{
    __shared__ __align__(16) half_t sm[3 * 6144];   // 3 bufs x 192 rows x 32 halves = 36 KB

    const int tid = threadIdx.x;
    const int wv = tid >> 6, ln = tid & 63;
    const int co0 = blockIdx.y * 128;
    const int wco = wv * 64;

    // XCD-chunked swizzle: contiguous px range per XCD (bijective, nx % 8 == 0)
    int bx = blockIdx.x;
    {
        const int cpx = gridDim.x >> 3;
        bx = (bx & 7) * cpx + (bx >> 3);
    }

    int eh = 0, ew = 0, p0;
    if (MODE == 2) {
        int q = bx / ptiles;
        p0 = (bx - q * ptiles) * 64;
        eh = q >> 1; ew = q & 1;
    } else {
        p0 = bx * 64;
    }

    const int Wd   = (MODE == 2) ? (Wout >> 1) : Wout;
    const int Hd   = (MODE == 2) ? (Hout >> 1) : Hout;
    const int PHW1 = Hd * Wd;
    const int NPX  = PHW1 * 32;          // batch 32 folded into px space
    const int K9   = KS * KS * CA;

    const int r  = tid >> 2;             // 0..31: row within a 32-row DMA class
    const int s4 = tid & 3;              // 16B slot
    const int sw = (s4 ^ (r & 3)) << 3;  // swizzled half-offset within 32-half chunk

    const size_t abase0 = (size_t)(co0 + r     ) * K9;
    const size_t abase1 = (size_t)(co0 + r + 32) * K9;
    const size_t abase2 = (size_t)(co0 + r + 64) * K9;
    const size_t abase3 = (size_t)(co0 + r + 96) * K9;

    int bph[2], bpw[2]; bool bval[2]; size_t bnb[2];
#pragma unroll
    for (int i = 0; i < 2; ++i) {
        int px = p0 + i * 32 + r;
        bval[i] = px < NPX;
        int pc = bval[i] ? px : 0;
        int n2 = pc / PHW1; int rem = pc - n2 * PHW1;
        int ph = rem / Wd;
        bph[i] = ph; bpw[i] = rem - ph * Wd;
        bnb[i] = (size_t)n2 * Hin * Win;
    }

    const int cpt = CA >> 5;             // 32-ch chunks per tap (4 or 8)
    const int lgc = (cpt == 8) ? 3 : 2;
    int ntap, lgj = 0, phh = 0, pww = 0;
    if (MODE == 2) {
        phh = (eh + 1) & 1; pww = (ew + 1) & 1;
        lgj = ew;
        ntap = (1 + eh) * (1 + ew);
    } else {
        ntap = KS * KS;
    }
    const int total = ntap << lgc;

    // issue one chunk's 6 DMA loads (4 x A-rows32, 2 x B-rows32) into dst buffer
    auto issue = [&](int flat, half_t* dst) {
        const int ci = flat & (cpt - 1);
        const int ti = flat >> lgc;
        int kh, kw;
        if (MODE == 2) {
            int i2 = ti >> lgj, j = ti & ((1 << lgj) - 1);
            kh = phh + 2 * i2; kw = pww + 2 * j;
        } else if (KS == 3) {
            kh = (ti * 11) >> 5; kw = ti - 3 * kh;   // div-by-3, ti<9
        } else { kh = 0; kw = 0; }
        const int c0 = ci << 5;
        const size_t koff = (size_t)(kh * KS + kw) * CA + c0 + sw;
        gll16(Ag + abase0 + koff, dst +        tid * 8);
        gll16(Ag + abase1 + koff, dst + 1024 + tid * 8);
        gll16(Ag + abase2 + koff, dst + 2048 + tid * 8);
        gll16(Ag + abase3 + koff, dst + 3072 + tid * 8);
#pragma unroll
        for (int i = 0; i < 2; ++i) {
            int hh, ww2; bool ok = bval[i];
            if (MODE == 0) {
                hh = bph[i] * S - PAD + kh; ww2 = bpw[i] * S - PAD + kw;
                ok = ok && (unsigned)hh < (unsigned)Hin && (unsigned)ww2 < (unsigned)Win;
            } else if (MODE == 1) {
                hh = bph[i] + PAD - kh; ww2 = bpw[i] + PAD - kw;
                ok = ok && (unsigned)hh < (unsigned)Hin && (unsigned)ww2 < (unsigned)Win;
            } else {
                int nh = 2 * bph[i] + eh + PAD - kh, nw = 2 * bpw[i] + ew + PAD - kw;
                hh = nh >> 1; ww2 = nw >> 1;
                ok = ok && nh >= 0 && nw >= 0 && hh < Hin && ww2 < Win;
            }
            const half_t* src = ok
                ? Xh + (bnb[i] + (size_t)(hh * Win + ww2)) * CA + c0 + sw
                : zpg;
            gll16(src, dst + 4096 + i * 1024 + tid * 8);
        }
    };

    f32x4 acc[4][4] = {};

    // prologue: chunks 0 and 1 in flight; wait oldest 6 (chunk 0), barrier
    issue(0, sm);
    issue(1, sm + 6144);
    VM_WAIT_BARRIER(6);

    const int fr = ln & 15, q8 = ln >> 4;
    const int rdA = (wco + fr) * 32 + ((q8 ^ (fr & 3)) << 3);
    const int rdB = (128 + fr) * 32 + ((q8 ^ (fr & 3)) << 3);

    int bi = 0;
    for (int k = 0; k < total; ++k) {
        half_t* bufr = sm + bi * 6144;
        if (k + 2 < total) {
            int b2 = bi + 2; if (b2 >= 3) b2 -= 3;
            issue(k + 2, sm + b2 * 6144);
        }
        half8 fa[4], fb[4];
#pragma unroll
        for (int m = 0; m < 4; ++m)
            fa[m] = *(const half8*)(bufr + rdA + m * 512);
#pragma unroll
        for (int t2 = 0; t2 < 4; ++t2)
            fb[t2] = *(const half8*)(bufr + rdB + t2 * 512);
#pragma unroll
        for (int m = 0; m < 4; ++m)
#pragma unroll
            for (int t2 = 0; t2 < 4; ++t2)
                acc[m][t2] = __builtin_amdgcn_mfma_f32_16x16x32_f16(fa[m], fb[t2], acc[m][t2], 0, 0, 0);
        if (k + 2 < total) {        // block-uniform
            VM_WAIT_BARRIER(6);
        } else if (k + 1 < total) {
            VM_WAIT_BARRIER(0);
        }
        bi = (bi == 2) ? 0 : bi + 1;
    }

    // epilogue
    const int rg = ln >> 4;
#pragma unroll
    for (int t = 0; t < 4; ++t) {
        int px = p0 + t * 16 + fr;
        if (px >= NPX) continue;
        int n2 = px / PHW1; int rem = px - n2 * PHW1;
        int ph = rem / Wd, pw = rem - ph * Wd;
        int oh, ow;
        if (MODE == 2) { oh = 2 * ph + eh; ow = 2 * pw + ew; }
        else           { oh = ph;          ow = pw; }
        size_t ghwc = ((size_t)(n2 * Hout + oh) * Wout + ow) * Cout;
#pragma unroll
        for (int m = 0; m < 4; ++m) {
#pragma unroll
            for (int rr = 0; rr < 4; ++rr) {
                int co_l = co0 + wco + m * 16 + rg * 4 + rr;
                size_t fidx = ((size_t)(n2 * Cout + co_l) * Hout + oh) * Wout + ow;
                float v = alpha * acc[m][t][rr] + delta;
                if (auxH) v += beta * (float)auxH[ghwc + co_l];
                if (auxF) v += beta * auxF[fidx];
                if (relu1) v = fmaxf(v, 0.f);
                if (pscale) v = pscale[co_l] * v + pbias[co_l];
                if (aux3) v += aux3[fidx];
                if (relu2) v = fmaxf(v, 0.f);
                if (outH) outH[ghwc + co_l] = (half_t)v;
                else      outF[fidx] = v;
            }
        }
    }
}

template<int KT>
__global__ __launch_bounds__(256)
void pack_w(const float* __restrict__ W, half_t* __restrict__ Wh,
            half_t* __restrict__ WTh, int Cin, int Cout, int do_norm)
{
    __shared__ float red[256];
    int co = blockIdx.x, tid = threadIdx.x;
    int CK = Cin * KT;
    const float* w = W + (size_t)co * CK;
    float inv = 1.f;
    if (do_norm) {
        float s = 0.f;
        for (int i = tid; i < CK; i += 256) { float v = w[i]; s += v * v; }
        red[tid] = s; __syncthreads();
        for (int o = 128; o > 0; o >>= 1) {
            if (tid < o) red[tid] += red[tid + o];
            __syncthreads();
        }
        inv = 1.f / (sqrtf(red[0]) + 1e-12f);
    }
    for (int i = tid; i < CK; i += 256) {
        int ci = i / KT, tap = i - ci * KT;
        half_t h = (half_t)(w[i] * inv);
        Wh[((size_t)co * KT + tap) * Cin + ci] = h;
        if (WTh) WTh[((size_t)ci * KT + tap) * Cout + co] = h;
    }
}

__global__ __launch_bounds__(256)
void tx_kernel(const float* __restrict__ x, half_t* __restrict__ xTh)
{
    __shared__ __align__(16) half_t tl[56 * 136];
    int h = blockIdx.x, n = blockIdx.y, tid = threadIdx.x;
    for (int it = 0; it < 28; ++it) {
        int id = tid + it * 256;
        int c = id / 56, w0 = id - c * 56;
        tl[w0 * 136 + c] = (half_t)x[(((size_t)n * 128 + c) * 56 + h) * 56 + w0];
    }
    __syncthreads();
    if (tid < 224) {
        int w0 = tid >> 2, part = tid & 3;
        size_t base = (((size_t)n * 56 + h) * 56 + w0) * 128 + part * 32;
#pragma unroll
        for (int j = 0; j < 4; ++j)
            *(half8*)(xTh + base + j * 8) = *(const half8*)(tl + w0 * 136 + part * 32 + j * 8);
    }
}

__global__ __launch_bounds__(256)
void comb_kernel(const half_t* __restrict__ c, const half_t* __restrict__ p,
                 half_t* __restrict__ a, float w1, float w2, int n8)
{
    int i = blockIdx.x * 256 + threadIdx.x;
    if (i >= n8) return;
    half8 cv = ((const half8*)c)[i];
    half8 pv = ((const half8*)p)[i];
    half8 rres;
#pragma unroll
    for (int j = 0; j < 8; ++j) rres[j] = (half_t)(w1 * (float)cv[j] + w2 * (float)pv[j]);
    ((half8*)a)[i] = rres;
}

__global__ __launch_bounds__(256)
void bn_prep_kernel(const float* __restrict__ g, const float* __restrict__ b,
                    const float* __restrict__ m, const float* __restrict__ v,
                    float* __restrict__ s, float* __restrict__ t, int C)
{
    int i = blockIdx.x * 256 + threadIdx.x;
    if (i < C) {
        float sc = g[i] * rsqrtf(v[i] + BN_EPS_F);
        s[i] = sc; t[i] = b[i] - m[i] * sc;
    }
}

__global__ __launch_bounds__(128)
void zfill_kernel(half_t* __restrict__ p)
{
    p[threadIdx.x] = (half_t)0.f;   // 256 B zero page for OOB DMA redirect
}

extern "C" void kernel_launch(void* const* d_in, const int* in_sizes, int n_in,
                              void* d_out, int out_size, void* d_ws, size_t ws_size,
                              hipStream_t stream)
{
    (void)in_sizes; (void)n_in; (void)out_size;
    const float* x    = (const float*)d_in[0];
    const float* W1   = (const float*)d_in[1];
    const float* W2   = (const float*)d_in[2];
    const float* Wsc  = (const float*)d_in[3];
    const float* bn1g = (const float*)d_in[4];
    const float* bn1b = (const float*)d_in[5];
    const float* bn1m = (const float*)d_in[6];
    const float* bn1v = (const float*)d_in[7];
    const float* bn2g = (const float*)d_in[8];
    const float* bn2b = (const float*)d_in[9];
    const float* bn2m = (const float*)d_in[10];
    const float* bn2v = (const float*)d_in[11];
    const float* bscg = (const float*)d_in[12];
    const float* bscb = (const float*)d_in[13];
    const float* bscm = (const float*)d_in[14];
    const float* bscv = (const float*)d_in[15];

    const size_t NB = (size_t)32 * 256 * 28 * 28;
    const size_t NX = (size_t)32 * 128 * 56 * 56;

    char* base = (char*)d_ws;
    size_t off = 0;
    auto alloc = [&](size_t nbytes) -> void* {
        void* r = base + off;
        off = (off + nbytes + 255) & ~(size_t)255;
        return r;
    };
    half_t* Wh1  = (half_t*)alloc(294912 * 2);
    half_t* WTh1 = (half_t*)alloc(294912 * 2);
    half_t* Wh2  = (half_t*)alloc(589824 * 2);
    half_t* WTh2 = (half_t*)alloc(589824 * 2);
    half_t* Wsch = (half_t*)alloc(32768 * 2);
    float* bn1s = (float*)alloc(256 * 4);  float* bn1t = (float*)alloc(256 * 4);
    float* bn2s = (float*)alloc(256 * 4);  float* bn2t = (float*)alloc(256 * 4);
    float* bscs = (float*)alloc(256 * 4);  float* bsct = (float*)alloc(256 * 4);
    half_t* zpg  = (half_t*)alloc(256);
    half_t* xTh  = (half_t*)alloc(NX * 2);   // aliased as r56h after shortcut+c0 consume it
    half_t* r56h = xTh;
    half_t* Pa   = (half_t*)alloc(NB * 2);
    half_t* Pb   = (half_t*)alloc(NB * 2);
    half_t* Pc   = (half_t*)alloc(NB * 2);
    half_t* Py   = (half_t*)alloc(NB * 2);
    half_t* r28h = (half_t*)alloc(NB * 2);
    float*  scF  = (float*)alloc(NB * 4);
    if (off > ws_size) return;

    float* outp = (float*)d_out;

    double t = 1.0; float al[3];
    for (int i = 0; i < 3; ++i) {
        double tn = (1.0 + sqrt(1.0 + 4.0 * t * t)) / 2.0;
        al[i] = (float)((t - 1.0) / tn); t = tn;
    }

    const dim3 blk(256);
    const dim3 cblk(128);
    const dim3 gB(392, 2, 1);      // 25088 px / 64 exact, 2 co-tiles (Cout=256)
    const dim3 gT2(1568, 1, 1);    // 4 quadrants x 392 px-tiles (Cout=128)
    const int n8 = (int)(NB / 8);
    const dim3 gC((n8 + 255) / 256);
    const float* NF = nullptr;
    const half_t* NH = nullptr;
    float* NFo = nullptr;
    half_t* NHo = nullptr;

    pack_w<9><<<256, blk, 0, stream>>>(W1, Wh1, WTh1, 128, 256, 1);
    pack_w<9><<<256, blk, 0, stream>>>(W2, Wh2, WTh2, 256, 256, 1);
    pack_w<1><<<256, blk, 0, stream>>>(Wsc, Wsch, nullptr, 128, 256, 0);
    bn_prep_kernel<<<1, blk, 0, stream>>>(bn1g, bn1b, bn1m, bn1v, bn1s, bn1t, 256);
    bn_prep_kernel<<<1, blk, 0, stream>>>(bn2g, bn2b, bn2m, bn2v, bn2s, bn2t, 256);
    bn_prep_kernel<<<1, blk, 0, stream>>>(bscg, bscb, bscm, bscv, bscs, bsct, 256);
    zfill_kernel<<<1, cblk, 0, stream>>>(zpg);
    tx_kernel<<<dim3(56, 32), blk, 0, stream>>>(x, xTh);

    // ================= Stage A: dict_conv(x, W1, stride 2) =================
    conv_big<3,2,1,0><<<gB, cblk, 0, stream>>>(Wh1, xTh, NFo, Pa, NH, NF,
        128, 256, 56, 56, 28, 28, 392, MU_F, 0.f, -SHRINK_F, 1, NF, NF, NF, 0, zpg);
    conv_big<1,2,0,0><<<gB, cblk, 0, stream>>>(Wsch, xTh, scF, NHo, NH, NF,
        128, 256, 56, 56, 28, 28, 392, 1.f, 0.f, 0.f, 0, bscs, bsct, NF, 0, zpg);

    conv_big<3,2,1,2><<<gT2, cblk, 0, stream>>>(WTh1, Pa, NFo, r56h, NH, x,
        256, 128, 28, 28, 56, 56, 392, -1.f, 1.f, 0.f, 0, NF, NF, NF, 0, zpg);
    conv_big<3,2,1,0><<<gB, cblk, 0, stream>>>(Wh1, r56h, NFo, Pb, Pa, NF,
        128, 256, 56, 56, 28, 28, 392, MU_F, 1.f, -SHRINK_F, 1, NF, NF, NF, 0, zpg);

    comb_kernel<<<gC, blk, 0, stream>>>(Pb, Pa, Pc, 1.f + al[1], -al[1], n8);
    conv_big<3,2,1,2><<<gT2, cblk, 0, stream>>>(WTh1, Pc, NFo, r56h, NH, x,
        256, 128, 28, 28, 56, 56, 392, -1.f, 1.f, 0.f, 0, NF, NF, NF, 0, zpg);
    conv_big<3,2,1,0><<<gB, cblk, 0, stream>>>(Wh1, r56h, NFo, Pa, Pc, NF,
        128, 256, 56, 56, 28, 28, 392, MU_F, 1.f, -SHRINK_F, 1, NF, NF, NF, 0, zpg);

    comb_kernel<<<gC, blk, 0, stream>>>(Pa, Pb, Pc, 1.f + al[2], -al[2], n8);
    conv_big<3,2,1,2><<<gT2, cblk, 0, stream>>>(WTh1, Pc, NFo, r56h, NH, x,
        256, 128, 28, 28, 56, 56, 392, -1.f, 1.f, 0.f, 0, NF, NF, NF, 0, zpg);
    conv_big<3,2,1,0><<<gB, cblk, 0, stream>>>(Wh1, r56h, NFo, Py, Pc, NF,
        128, 256, 56, 56, 28, 28, 392, MU_F, 1.f, -SHRINK_F, 1, bn1s, bn1t, NF, 0, zpg);

    // ================= Stage B: dict_conv(y1, W2, stride 1) ================
    conv_big<3,1,1,0><<<gB, cblk, 0, stream>>>(Wh2, Py, NFo, Pa, NH, NF,
        256, 256, 28, 28, 28, 28, 392, MU_F, 0.f, -SHRINK_F, 1, NF, NF, NF, 0, zpg);

    conv_big<3,1,1,1><<<gB, cblk, 0, stream>>>(WTh2, Pa, NFo, r28h, Py, NF,
        256, 256, 28, 28, 28, 28, 392, -1.f, 1.f, 0.f, 0, NF, NF, NF, 0, zpg);
    conv_big<3,1,1,0><<<gB, cblk, 0, stream>>>(Wh2, r28h, NFo, Pb, Pa, NF,
        256, 256, 28, 28, 28, 28, 392, MU_F, 1.f, -SHRINK_F, 1, NF, NF, NF, 0, zpg);

    comb_kernel<<<gC, blk, 0, stream>>>(Pb, Pa, Pc, 1.f + al[1], -al[1], n8);
    conv_big<3,1,1,1><<<gB, cblk, 0, stream>>>(WTh2, Pc, NFo, r28h, Py, NF,
        256, 256, 28, 28, 28, 28, 392, -1.f, 1.f, 0.f, 0, NF, NF, NF, 0, zpg);
    conv_big<3,1,1,0><<<gB, cblk, 0, stream>>>(Wh2, r28h, NFo, Pa, Pc, NF,
        256, 256, 28, 28, 28, 28, 392, MU_F, 1.f, -SHRINK_F, 1, NF, NF, NF, 0, zpg);

    comb_kernel<<<gC, blk, 0, stream>>>(Pa, Pb, Pc, 1.f + al[2], -al[2], n8);
    conv_big<3,1,1,1><<<gT2.x ? gB : gB, cblk, 0, stream>>>(WTh2, Pc, NFo, r28h, Py, NF,
        256, 256, 28, 28, 28, 28, 392, -1.f, 1.f, 0.f, 0, NF, NF, NF, 0, zpg);
    conv_big<3,1,1,0><<<gB, cblk, 0, stream>>>(Wh2, r28h, outp, NHo, Pc, NF,
        256, 256, 28, 28, 28, 28, 392, MU_F, 1.f, -SHRINK_F, 1, bn2s, bn2t, scF, 1, zpg);
}

// Round 3
// 1236.357 us; speedup vs baseline: 1.1106x; 1.0464x over previous
//
#include <hip/hip_runtime.h>
#include <math.h>

#define MU_F 0.1f
#define SHRINK_F 0.01f   // LMBD * MU
#define BN_EPS_F 1e-5f

typedef _Float16 half_t;
typedef _Float16 half8 __attribute__((ext_vector_type(8)));
typedef float f32x4 __attribute__((ext_vector_type(4)));

// async global->LDS, 16B per lane. LDS dest is wave-uniform base + lane*16.
__device__ __forceinline__ void gll16(const half_t* g, half_t* l) {
    __builtin_amdgcn_global_load_lds(
        (const __attribute__((address_space(1))) void*)g,
        (__attribute__((address_space(3))) void*)l, 16, 0, 0);
}

// counted-vmcnt wait + raw barrier, split per the verified 8-phase idiom
// (separate asm statements + sched_barrier(0) fence; rule #18 hygiene).
#define VM_WAIT_BARRIER(N) do {                                   \
    asm volatile("s_waitcnt vmcnt(" #N ")" ::: "memory");         \
    __builtin_amdgcn_s_barrier();                                 \
    __builtin_amdgcn_sched_barrier(0);                            \
} while (0)

// ---------------------------------------------------------------------------
// MFMA implicit-GEMM conv, m97-tile + T3/T4 deep async pipeline:
//   block = 128co x 128px (batch folded into px: NPX = 32*Hd*Wd = 25088,
//   exact 128-tiles -> 196 px-tiles, no dead blocks)
//   4 waves (2co x 2px) of 64x64 -> 16 MFMA : 4 DMA per wave per chunk (K=32)
//   staging via global_load_lds dwordx4 into FOUR LDS buffers (16KB each),
//   lookahead 3: chunk k+3 issued at iter k; steady-state s_waitcnt vmcnt(8)
//   (12 in flight, oldest chunk's 4 retired), tail ladder 8->4->0.
//   Ring R=4 >= lookahead+1: buffer written at k was last read at k-1,
//   behind a barrier -> no WAR hazard.
//   OOB taps -> 256B zero page (DMA is unconditional per row).
//   LDS: 256 rows x 64B linear (A rows 0..127, B rows 128..255); 16B slot
//   XOR-swizzle (slot = q ^ (row&3)) applied on global SOURCE and on ds_read
//   (same involution both sides, rule 21).
//   Bijective XCD swizzle (m204 form; gridDim.x need not be %8).
// MODE 0: fwd conv stride S pad PAD; MODE 1: convT s1 (pad 1);
// MODE 2: convT s2 (pad 1, outpad 1) via parity-quadrant px mapping.
// Frag layout (16x16x32): A row=l&15, k=(l>>4)*8+j ; B col=l&15 same k;
// C/D col=l&15, row=(l>>4)*4+reg  [m89-verified].
// ---------------------------------------------------------------------------
template<int KS, int S, int PAD, int MODE>
__global__ __launch_bounds__(256, 2)
void conv_big(const half_t* __restrict__ Ag, const half_t* __restrict__ Xh,
              float* __restrict__ outF, half_t* __restrict__ outH,
              const half_t* __restrict__ auxH, const float* __restrict__ auxF,
              int CA, int Cout, int Hin, int Win, int Hout, int Wout, int ptiles,
              float alpha, float beta, float delta, int relu1,
              const float* __restrict__ pscale, const float* __restrict__ pbias,
              const float* __restrict__ aux3, int relu2,
              const half_t* __restrict__ zpg)
{
    __shared__ __align__(16) half_t sm[4 * 8192];   // 4 bufs x 256 rows x 32 halves = 64 KB

    const int tid = threadIdx.x;
    const int wv = tid >> 6, ln = tid & 63;
    const int co0 = blockIdx.y * 128;
    const int wco = (wv & 1) * 64, wpx = (wv >> 1) * 64;

    // bijective XCD swizzle (m204): works for any gridDim.x
    int bx;
    {
        const int nwg = gridDim.x;
        const int q = nwg >> 3, r8 = nwg & 7;
        const int xcd = blockIdx.x & 7, idx = blockIdx.x >> 3;
        bx = (xcd < r8 ? xcd * (q + 1) : r8 * (q + 1) + (xcd - r8) * q) + idx;
    }

    int eh = 0, ew = 0, p0;
    if (MODE == 2) {
        int qq = bx / ptiles;
        p0 = (bx - qq * ptiles) * 128;
        eh = qq >> 1; ew = qq & 1;
    } else {
        p0 = bx * 128;
    }

    const int Wd   = (MODE == 2) ? (Wout >> 1) : Wout;
    const int Hd   = (MODE == 2) ? (Hout >> 1) : Hout;
    const int PHW1 = Hd * Wd;
    const int NPX  = PHW1 * 32;          // batch 32 folded into px space
    const int K9   = KS * KS * CA;

    const int r  = tid >> 2;             // 0..63: row within a 64-row DMA pass
    const int s4 = tid & 3;              // 16B slot
    const int sw = (s4 ^ (r & 3)) << 3;  // swizzled half-offset within 32-half chunk

    const size_t abase0 = (size_t)(co0 + r     ) * K9;   // A pass 0: co rows 0..63
    const size_t abase1 = (size_t)(co0 + r + 64) * K9;   // A pass 1: co rows 64..127

    int bph[2], bpw[2]; bool bval[2]; size_t bnb[2];
#pragma unroll
    for (int i = 0; i < 2; ++i) {
        int px = p0 + i * 64 + r;
        bval[i] = px < NPX;
        int pc = bval[i] ? px : 0;
        int n2 = pc / PHW1; int rem = pc - n2 * PHW1;
        int ph = rem / Wd;
        bph[i] = ph; bpw[i] = rem - ph * Wd;
        bnb[i] = (size_t)n2 * Hin * Win;
    }

    const int cpt = CA >> 5;             // 32-ch chunks per tap (4 or 8)
    const int lgc = (cpt == 8) ? 3 : 2;
    int ntap, lgj = 0, phh = 0, pww = 0;
    if (MODE == 2) {
        phh = (eh + 1) & 1; pww = (ew + 1) & 1;
        lgj = ew;
        ntap = (1 + eh) * (1 + ew);
    } else {
        ntap = KS * KS;
    }
    const int total = ntap << lgc;       // >= 4 at every call site

    // issue one chunk's 4 DMA passes (2 x A 64-rows, 2 x B 64-rows) into dst
    auto issue = [&](int flat, half_t* dst) {
        const int ci = flat & (cpt - 1);
        const int ti = flat >> lgc;
        int kh, kw;
        if (MODE == 2) {
            int i2 = ti >> lgj, j = ti & ((1 << lgj) - 1);
            kh = phh + 2 * i2; kw = pww + 2 * j;
        } else if (KS == 3) {
            kh = (ti * 11) >> 5; kw = ti - 3 * kh;   // div-by-3, ti<9
        } else { kh = 0; kw = 0; }
        const int c0 = ci << 5;
        const size_t koff = (size_t)(kh * KS + kw) * CA + c0 + sw;
        gll16(Ag + abase0 + koff, dst +        tid * 8);
        gll16(Ag + abase1 + koff, dst + 2048 + tid * 8);
#pragma unroll
        for (int i = 0; i < 2; ++i) {
            int hh, ww2; bool ok = bval[i];
            if (MODE == 0) {
                hh = bph[i] * S - PAD + kh; ww2 = bpw[i] * S - PAD + kw;
                ok = ok && (unsigned)hh < (unsigned)Hin && (unsigned)ww2 < (unsigned)Win;
            } else if (MODE == 1) {
                hh = bph[i] + PAD - kh; ww2 = bpw[i] + PAD - kw;
                ok = ok && (unsigned)hh < (unsigned)Hin && (unsigned)ww2 < (unsigned)Win;
            } else {
                int nh = 2 * bph[i] + eh + PAD - kh, nw = 2 * bpw[i] + ew + PAD - kw;
                hh = nh >> 1; ww2 = nw >> 1;
                ok = ok && nh >= 0 && nw >= 0 && hh < Hin && ww2 < Win;
            }
            const half_t* src = ok
                ? Xh + (bnb[i] + (size_t)(hh * Win + ww2)) * CA + c0 + sw
                : zpg;
            gll16(src, dst + 4096 + i * 2048 + tid * 8);
        }
    };

    f32x4 acc[4][4] = {};

    // prologue: chunks 0,1,2 in flight (12 instr); wait oldest 4, barrier
    issue(0, sm);
    issue(1, sm + 8192);
    issue(2, sm + 16384);
    VM_WAIT_BARRIER(8);

    const int fr = ln & 15, q8 = ln >> 4;
    const int sx = (q8 ^ (fr & 3)) << 3;
    const int rdA = (wco + fr) * 32 + sx;
    const int rdB = (128 + wpx + fr) * 32 + sx;

    for (int k = 0; k < total; ++k) {
        half_t* bufr = sm + (k & 3) * 8192;
        if (k + 3 < total)
            issue(k + 3, sm + ((k + 3) & 3) * 8192);
        half8 fa[4], fb[4];
#pragma unroll
        for (int m = 0; m < 4; ++m)
            fa[m] = *(const half8*)(bufr + rdA + m * 512);
#pragma unroll
        for (int t2 = 0; t2 < 4; ++t2)
            fb[t2] = *(const half8*)(bufr + rdB + t2 * 512);
#pragma unroll
        for (int m = 0; m < 4; ++m)
#pragma unroll
            for (int t2 = 0; t2 < 4; ++t2)
                acc[m][t2] = __builtin_amdgcn_mfma_f32_16x16x32_f16(fa[m], fb[t2], acc[m][t2], 0, 0, 0);
        // block-uniform branch ladder (total, k uniform)
        if (k + 3 < total)      VM_WAIT_BARRIER(8);   // ensure chunk k+1 landed
        else if (k + 2 < total) VM_WAIT_BARRIER(4);
        else if (k + 1 < total) VM_WAIT_BARRIER(0);
    }

    // epilogue
    const int rg = ln >> 4;
#pragma unroll
    for (int t = 0; t < 4; ++t) {
        int px = p0 + wpx + t * 16 + fr;
        if (px >= NPX) continue;
        int n2 = px / PHW1; int rem = px - n2 * PHW1;
        int ph = rem / Wd, pw = rem - ph * Wd;
        int oh, ow;
        if (MODE == 2) { oh = 2 * ph + eh; ow = 2 * pw + ew; }
        else           { oh = ph;          ow = pw; }
        size_t ghwc = ((size_t)(n2 * Hout + oh) * Wout + ow) * Cout;
#pragma unroll
        for (int m = 0; m < 4; ++m) {
#pragma unroll
            for (int rr = 0; rr < 4; ++rr) {
                int co_l = co0 + wco + m * 16 + rg * 4 + rr;
                size_t fidx = ((size_t)(n2 * Cout + co_l) * Hout + oh) * Wout + ow;
                float v = alpha * acc[m][t][rr] + delta;
                if (auxH) v += beta * (float)auxH[ghwc + co_l];
                if (auxF) v += beta * auxF[fidx];
                if (relu1) v = fmaxf(v, 0.f);
                if (pscale) v = pscale[co_l] * v + pbias[co_l];
                if (aux3) v += aux3[fidx];
                if (relu2) v = fmaxf(v, 0.f);
                if (outH) outH[ghwc + co_l] = (half_t)v;
                else      outF[fidx] = v;
            }
        }
    }
}

template<int KT>
__global__ __launch_bounds__(256)
void pack_w(const float* __restrict__ W, half_t* __restrict__ Wh,
            half_t* __restrict__ WTh, int Cin, int Cout, int do_norm)
{
    __shared__ float red[256];
    int co = blockIdx.x, tid = threadIdx.x;
    int CK = Cin * KT;
    const float* w = W + (size_t)co * CK;
    float inv = 1.f;
    if (do_norm) {
        float s = 0.f;
        for (int i = tid; i < CK; i += 256) { float v = w[i]; s += v * v; }
        red[tid] = s; __syncthreads();
        for (int o = 128; o > 0; o >>= 1) {
            if (tid < o) red[tid] += red[tid + o];
            __syncthreads();
        }
        inv = 1.f / (sqrtf(red[0]) + 1e-12f);
    }
    for (int i = tid; i < CK; i += 256) {
        int ci = i / KT, tap = i - ci * KT;
        half_t h = (half_t)(w[i] * inv);
        Wh[((size_t)co * KT + tap) * Cin + ci] = h;
        if (WTh) WTh[((size_t)ci * KT + tap) * Cout + co] = h;
    }
}

__global__ __launch_bounds__(256)
void tx_kernel(const float* __restrict__ x, half_t* __restrict__ xTh)
{
    __shared__ __align__(16) half_t tl[56 * 136];
    int h = blockIdx.x, n = blockIdx.y, tid = threadIdx.x;
    for (int it = 0; it < 28; ++it) {
        int id = tid + it * 256;
        int c = id / 56, w0 = id - c * 56;
        tl[w0 * 136 + c] = (half_t)x[(((size_t)n * 128 + c) * 56 + h) * 56 + w0];
    }
    __syncthreads();
    if (tid < 224) {
        int w0 = tid >> 2, part = tid & 3;
        size_t base = (((size_t)n * 56 + h) * 56 + w0) * 128 + part * 32;
#pragma unroll
        for (int j = 0; j < 4; ++j)
            *(half8*)(xTh + base + j * 8) = *(const half8*)(tl + w0 * 136 + part * 32 + j * 8);
    }
}

__global__ __launch_bounds__(256)
void comb_kernel(const half_t* __restrict__ c, const half_t* __restrict__ p,
                 half_t* __restrict__ a, float w1, float w2, int n8)
{
    int i = blockIdx.x * 256 + threadIdx.x;
    if (i >= n8) return;
    half8 cv = ((const half8*)c)[i];
    half8 pv = ((const half8*)p)[i];
    half8 rres;
#pragma unroll
    for (int j = 0; j < 8; ++j) rres[j] = (half_t)(w1 * (float)cv[j] + w2 * (float)pv[j]);
    ((half8*)a)[i] = rres;
}

__global__ __launch_bounds__(256)
void bn_prep_kernel(const float* __restrict__ g, const float* __restrict__ b,
                    const float* __restrict__ m, const float* __restrict__ v,
                    float* __restrict__ s, float* __restrict__ t, int C)
{
    int i = blockIdx.x * 256 + threadIdx.x;
    if (i < C) {
        float sc = g[i] * rsqrtf(v[i] + BN_EPS_F);
        s[i] = sc; t[i] = b[i] - m[i] * sc;
    }
}

__global__ __launch_bounds__(128)
void zfill_kernel(half_t* __restrict__ p)
{
    p[threadIdx.x] = (half_t)0.f;   // 256 B zero page for OOB DMA redirect
}

extern "C" void kernel_launch(void* const* d_in, const int* in_sizes, int n_in,
                              void* d_out, int out_size, void* d_ws, size_t ws_size,
                              hipStream_t stream)
{
    (void)in_sizes; (void)n_in; (void)out_size;
    const float* x    = (const float*)d_in[0];
    const float* W1   = (const float*)d_in[1];
    const float* W2   = (const float*)d_in[2];
    const float* Wsc  = (const float*)d_in[3];
    const float* bn1g = (const float*)d_in[4];
    const float* bn1b = (const float*)d_in[5];
    const float* bn1m = (const float*)d_in[6];
    const float* bn1v = (const float*)d_in[7];
    const float* bn2g = (const float*)d_in[8];
    const float* bn2b = (const float*)d_in[9];
    const float* bn2m = (const float*)d_in[10];
    const float* bn2v = (const float*)d_in[11];
    const float* bscg = (const float*)d_in[12];
    const float* bscb = (const float*)d_in[13];
    const float* bscm = (const float*)d_in[14];
    const float* bscv = (const float*)d_in[15];

    const size_t NB = (size_t)32 * 256 * 28 * 28;
    const size_t NX = (size_t)32 * 128 * 56 * 56;

    char* base = (char*)d_ws;
    size_t off = 0;
    auto alloc = [&](size_t nbytes) -> void* {
        void* r = base + off;
        off = (off + nbytes + 255) & ~(size_t)255;
        return r;
    };
    half_t* Wh1  = (half_t*)alloc(294912 * 2);
    half_t* WTh1 = (half_t*)alloc(294912 * 2);
    half_t* Wh2  = (half_t*)alloc(589824 * 2);
    half_t* WTh2 = (half_t*)alloc(589824 * 2);
    half_t* Wsch = (half_t*)alloc(32768 * 2);
    float* bn1s = (float*)alloc(256 * 4);  float* bn1t = (float*)alloc(256 * 4);
    float* bn2s = (float*)alloc(256 * 4);  float* bn2t = (float*)alloc(256 * 4);
    float* bscs = (float*)alloc(256 * 4);  float* bsct = (float*)alloc(256 * 4);
    half_t* zpg  = (half_t*)alloc(256);
    half_t* xTh  = (half_t*)alloc(NX * 2);   // aliased as r56h after shortcut+c0 consume it
    half_t* r56h = xTh;
    half_t* Pa   = (half_t*)alloc(NB * 2);
    half_t* Pb   = (half_t*)alloc(NB * 2);
    half_t* Pc   = (half_t*)alloc(NB * 2);
    half_t* Py   = (half_t*)alloc(NB * 2);
    half_t* r28h = (half_t*)alloc(NB * 2);
    float*  scF  = (float*)alloc(NB * 4);
    if (off > ws_size) return;

    float* outp = (float*)d_out;

    double t = 1.0; float al[3];
    for (int i = 0; i < 3; ++i) {
        double tn = (1.0 + sqrt(1.0 + 4.0 * t * t)) / 2.0;
        al[i] = (float)((t - 1.0) / tn); t = tn;
    }

    const dim3 blk(256);
    const dim3 cblk(256);
    const dim3 gB(196, 2, 1);      // 25088 px / 128 exact, 2 co-tiles (Cout=256)
    const dim3 gT2(784, 1, 1);     // 4 quadrants x 196 px-tiles (Cout=128)
    const int n8 = (int)(NB / 8);
    const dim3 gC((n8 + 255) / 256);
    const float* NF = nullptr;
    const half_t* NH = nullptr;
    float* NFo = nullptr;
    half_t* NHo = nullptr;

    pack_w<9><<<256, blk, 0, stream>>>(W1, Wh1, WTh1, 128, 256, 1);
    pack_w<9><<<256, blk, 0, stream>>>(W2, Wh2, WTh2, 256, 256, 1);
    pack_w<1><<<256, blk, 0, stream>>>(Wsc, Wsch, nullptr, 128, 256, 0);
    bn_prep_kernel<<<1, blk, 0, stream>>>(bn1g, bn1b, bn1m, bn1v, bn1s, bn1t, 256);
    bn_prep_kernel<<<1, blk, 0, stream>>>(bn2g, bn2b, bn2m, bn2v, bn2s, bn2t, 256);
    bn_prep_kernel<<<1, blk, 0, stream>>>(bscg, bscb, bscm, bscv, bscs, bsct, 256);
    zfill_kernel<<<1, dim3(128), 0, stream>>>(zpg);
    tx_kernel<<<dim3(56, 32), blk, 0, stream>>>(x, xTh);

    // ================= Stage A: dict_conv(x, W1, stride 2) =================
    conv_big<3,2,1,0><<<gB, cblk, 0, stream>>>(Wh1, xTh, NFo, Pa, NH, NF,
        128, 256, 56, 56, 28, 28, 196, MU_F, 0.f, -SHRINK_F, 1, NF, NF, NF, 0, zpg);
    conv_big<1,2,0,0><<<gB, cblk, 0, stream>>>(Wsch, xTh, scF, NHo, NH, NF,
        128, 256, 56, 56, 28, 28, 196, 1.f, 0.f, 0.f, 0, bscs, bsct, NF, 0, zpg);

    conv_big<3,2,1,2><<<gT2, cblk, 0, stream>>>(WTh1, Pa, NFo, r56h, NH, x,
        256, 128, 28, 28, 56, 56, 196, -1.f, 1.f, 0.f, 0, NF, NF, NF, 0, zpg);
    conv_big<3,2,1,0><<<gB, cblk, 0, stream>>>(Wh1, r56h, NFo, Pb, Pa, NF,
        128, 256, 56, 56, 28, 28, 196, MU_F, 1.f, -SHRINK_F, 1, NF, NF, NF, 0, zpg);

    comb_kernel<<<gC, blk, 0, stream>>>(Pb, Pa, Pc, 1.f + al[1], -al[1], n8);
    conv_big<3,2,1,2><<<gT2, cblk, 0, stream>>>(WTh1, Pc, NFo, r56h, NH, x,
        256, 128, 28, 28, 56, 56, 196, -1.f, 1.f, 0.f, 0, NF, NF, NF, 0, zpg);
    conv_big<3,2,1,0><<<gB, cblk, 0, stream>>>(Wh1, r56h, NFo, Pa, Pc, NF,
        128, 256, 56, 56, 28, 28, 196, MU_F, 1.f, -SHRINK_F, 1, NF, NF, NF, 0, zpg);

    comb_kernel<<<gC, blk, 0, stream>>>(Pa, Pb, Pc, 1.f + al[2], -al[2], n8);
    conv_big<3,2,1,2><<<gT2, cblk, 0, stream>>>(WTh1, Pc, NFo, r56h, NH, x,
        256, 128, 28, 28, 56, 56, 196, -1.f, 1.f, 0.f, 0, NF, NF, NF, 0, zpg);
    conv_big<3,2,1,0><<<gB, cblk, 0, stream>>>(Wh1, r56h, NFo, Py, Pc, NF,
        128, 256, 56, 56, 28, 28, 196, MU_F, 1.f, -SHRINK_F, 1, bn1s, bn1t, NF, 0, zpg);

    // ================= Stage B: dict_conv(y1, W2, stride 1) ================
    conv_big<3,1,1,0><<<gB, cblk, 0, stream>>>(Wh2, Py, NFo, Pa, NH, NF,
        256, 256, 28, 28, 28, 28, 196, MU_F, 0.f, -SHRINK_F, 1, NF, NF, NF, 0, zpg);

    conv_big<3,1,1,1><<<gB, cblk, 0, stream>>>(WTh2, Pa, NFo, r28h, Py, NF,
        256, 256, 28, 28, 28, 28, 196, -1.f, 1.f, 0.f, 0, NF, NF, NF, 0, zpg);
    conv_big<3,1,1,0><<<gB, cblk, 0, stream>>>(Wh2, r28h, NFo, Pb, Pa, NF,
        256, 256, 28, 28, 28, 28, 196, MU_F, 1.f, -SHRINK_F, 1, NF, NF, NF, 0, zpg);

    comb_kernel<<<gC, blk, 0, stream>>>(Pb, Pa, Pc, 1.f + al[1], -al[1], n8);
    conv_big<3,1,1,1><<<gB, cblk, 0, stream>>>(WTh2, Pc, NFo, r28h, Py, NF,
        256, 256, 28, 28, 28, 28, 196, -1.f, 1.f, 0.f, 0, NF, NF, NF, 0, zpg);
    conv_big<3,1,1,0><<<gB, cblk, 0, stream>>>(Wh2, r28h, NFo, Pa, Pc, NF,
        256, 256, 28, 28, 28, 28, 196, MU_F, 1.f, -SHRINK_F, 1, NF, NF, NF, 0, zpg);

    comb_kernel<<<gC, blk, 0, stream>>>(Pa, Pb, Pc, 1.f + al[2], -al[2], n8);
    conv_big<3,1,1,1><<<gB, cblk, 0, stream>>>(WTh2, Pc, NFo, r28h, Py, NF,
        256, 256, 28, 28, 28, 28, 196, -1.f, 1.f, 0.f, 0, NF, NF, NF, 0, zpg);
    conv_big<3,1,1,0><<<gB, cblk, 0, stream>>>(Wh2, r28h, outp, NHo, Pc, NF,
        256, 256, 28, 28, 28, 28, 196, MU_F, 1.f, -SHRINK_F, 1, bn2s, bn2t, scF, 1, zpg);
}